// Round 7
// baseline (39.323 us; speedup 1.0000x reference)
//
#include <hip/hip_runtime.h>

#define SURV_EPS 1e-7f
#define T_BINS 32
#define NBLOCKS 2048
#define NTHREADS 256
#define F32_MIN_NORMAL 1.17549435e-38f

// Kernel 1: grid-stride over PAIRS of float4 chunks (32B contiguous per thread,
// pairs never cross a row: 4 pairs per 32-bin row). Per pair: one int2 target
// load, one window test, one __logf of the 8-term selected product (clamped to
// min-normal to close the theoretical underflow->inf path; never binds on
// uniform data).
// History: R3 last-block fusion = +90us (2048 agent-scope atomics + L2 wb/inv
// per block on 8-XCD CDNA4 -- never again). R4 far-stride 2x unroll = -2us.
// R5 window-skip = neutral (rows are exactly one 128B line; VALU cuts neutral).
__global__ __launch_bounds__(NTHREADS) void surv_loss_partial(
    const float* __restrict__ preds,
    const int* __restrict__ targets,
    double* __restrict__ partial,
    int n_rows)
{
    const int n_pairs = n_rows * (T_BINS / 8);   // 4 pairs per row
    const float4* __restrict__ p4 = reinterpret_cast<const float4*>(preds);
    const int2*   __restrict__ t2 = reinterpret_cast<const int2*>(targets);

    double acc = 0.0;

    for (int u = blockIdx.x * blockDim.x + threadIdx.x; u < n_pairs;
         u += gridDim.x * blockDim.x) {
        const int r  = u >> 2;        // row (4 pairs per row)
        const int jb = (u & 3) << 3;  // first bin index of this 8-bin pair

        const int2 tg = t2[r];        // 4 lanes share a row -> L1 broadcast
        int t_i = tg.x;
        t_i = t_i < 1 ? 1 : (t_i > T_BINS ? T_BINS : t_i);
        const bool evb = (tg.y != 0);
        // used-bin window [lo, hi):  event: [t_i-1, T); censored: [0, t_i)
        const int lo = evb ? (t_i - 1) : 0;
        const int hi = evb ? T_BINS    : t_i;

        // Skip both loads + math when [jb, jb+8) misses [lo, hi).
        if ((jb + 8 > lo) & (jb < hi)) {
            const float4 a = p4[2 * u];
            const float4 b = p4[2 * u + 1];
            const float pv[8] = {a.x, a.y, a.z, a.w, b.x, b.y, b.z, b.w};
            float prod = 1.0f;
#pragma unroll
            for (int k = 0; k < 8; ++k) {
                const int j = jb + k;
                const float h = fminf(fmaxf(pv[k], SURV_EPS), 1.0f - SURV_EPS);
                const float x = evb ? h : (1.0f - h);  // both in [eps, 1-eps]
                const bool use = (j >= lo) & (j < hi);
                prod *= use ? x : 1.0f;
            }
            prod = fmaxf(prod, F32_MIN_NORMAL);  // close underflow->inf path
            acc -= (double)__logf(prod);
        }
    }

    __shared__ double sm[NTHREADS];
    const int tid = threadIdx.x;
    sm[tid] = acc;
    __syncthreads();
#pragma unroll
    for (int sN = NTHREADS / 2; sN > 0; sN >>= 1) {
        if (tid < sN) sm[tid] += sm[tid + sN];
        __syncthreads();
    }
    if (tid == 0) partial[blockIdx.x] = sm[0];
}

// Kernel 2: single block reduces the per-block partials, writes mean as f32.
__global__ __launch_bounds__(NTHREADS) void surv_loss_finish(
    const double* __restrict__ partial,
    float* __restrict__ out,
    int n_partials,
    int n_rows)
{
    const int tid = threadIdx.x;
    double acc = 0.0;
    for (int i = tid; i < n_partials; i += NTHREADS) acc += partial[i];

    __shared__ double sm[NTHREADS];
    sm[tid] = acc;
    __syncthreads();
#pragma unroll
    for (int sN = NTHREADS / 2; sN > 0; sN >>= 1) {
        if (tid < sN) sm[tid] += sm[tid + sN];
        __syncthreads();
    }
    if (tid == 0) out[0] = (float)(sm[0] / (double)n_rows);
}

extern "C" void kernel_launch(void* const* d_in, const int* in_sizes, int n_in,
                              void* d_out, int out_size, void* d_ws, size_t ws_size,
                              hipStream_t stream) {
    const float* preds   = (const float*)d_in[0];
    const int*   targets = (const int*)d_in[1];
    const int n_rows = in_sizes[0] / T_BINS;   // 1,500,000

    double* partial = (double*)d_ws;           // NBLOCKS doubles = 16 KiB
    float*  out     = (float*)d_out;

    surv_loss_partial<<<NBLOCKS, NTHREADS, 0, stream>>>(preds, targets, partial, n_rows);
    surv_loss_finish<<<1, NTHREADS, 0, stream>>>(partial, out, NBLOCKS, n_rows);
}